// Round 12
// baseline (721.571 us; speedup 1.0000x reference)
//
#include <hip/hip_runtime.h>

#define L_ 2
#define T_ 512
#define B_ 128
#define F_ 4
#define H_ 256
#define QSIGN_MASK 0x5390
#define KB_ 8          // mailbox batch (steps per publish/poll)

typedef __attribute__((ext_vector_type(8))) short short8;
typedef __attribute__((ext_vector_type(4))) float f32x4;

// Mailbox: layer-0 normalized output, bf16x4 packed per (t,b); norm-1 => at least
// one |comp| >= 0.5 => qword never 0. Zeroed every call.
__device__ unsigned long long g_mbq[T_][B_];

__global__ void zero_mb() {
  ((unsigned long long*)g_mbq)[blockIdx.x * 256 + threadIdx.x] = 0ull;
}

__device__ __forceinline__ unsigned f2bf(float f) {
  unsigned u = __float_as_uint(f);
  return (u + 0x7fff + ((u >> 16) & 1)) >> 16;
}
__device__ __forceinline__ float fast_sigmoid(float x) { return 1.f / (1.f + __expf(-x)); }
__device__ __forceinline__ float fast_tanh(float x) {
  float a = fabsf(x), e = __expf(2.f * a);
  return copysignf(1.f - 2.f / (e + 1.f), x);
}
__device__ __forceinline__ unsigned long long pack4bf(float a, float b, float c, float d) {
  return (unsigned long long)f2bf(a)
       | ((unsigned long long)f2bf(b) << 16)
       | ((unsigned long long)f2bf(c) << 32)
       | ((unsigned long long)f2bf(d) << 48);
}

union FragU { short8 v; uint4 u; unsigned w[4]; };

// Grid = 64 WGs x 320 threads (5 waves). blockIdx<32: layer-0 producer; else
// layer-1 consumer (same bg). Compute waves 0-3 (wave w -> u-cols [16w,16w+16)):
// MFMA M rows = b*4+q, N = u16, 4 accumulator sets (one per gate) -> LSTM update
// fully in-lane, zero shuffles, one barrier/iter. Bias in acc init; x-term = 1
// MFMA per gate from packed-bf16 x in LDS.
// Helper wave 4: per-iter projection of h[i-1] via MFMA (producer), results held
// in LDS; mailbox batched by KB_=8.
// KEY R12 change: amdgpu_waves_per_eu(2,2) pins the allocator to a 256-reg/wave
// budget (R11's heuristic capped at 128 -> Bf spilled to scratch, reloaded every
// iteration = the ~3100 cyc/step pacer).
__global__ void __launch_bounds__(320)
__attribute__((amdgpu_waves_per_eu(2, 2)))
qlstm_pipe(const float* __restrict__ x_in,
           const float* __restrict__ uhr, const float* __restrict__ uhi,
           const float* __restrict__ uhj, const float* __restrict__ uhk,
           const float* __restrict__ wxr, const float* __restrict__ wxi,
           const float* __restrict__ wxj, const float* __restrict__ wxk,
           const float* __restrict__ wxb_all,
           const float* __restrict__ fcw_all, const float* __restrict__ fcb_all,
           float* __restrict__ out_final)
{
  __shared__ unsigned long long sh_xq[T_][4];               // 16 KB x (bf16x4 packed)
  __shared__ __align__(16) unsigned short sh_h[2][4][272];  // 4.25 KB h dbuf
  __shared__ unsigned long long sh_hold[KB_][4];            // 256 B held projections

  const int t    = threadIdx.x;
  const int role = blockIdx.x >> 5;
  const int bg   = blockIdx.x & 31;
  const int bg0  = bg * 4;
  const int lyr  = role;
  const int wv   = t >> 6;
  const int lane = t & 63;
  const int quad = lane >> 4;
  const int sub  = lane & 15;

  for (int i = t; i < 2 * 4 * 272; i += 320) ((unsigned short*)sh_h)[i] = 0;

  if (role == 0) {
    // preload full x sequence (packed bf16x4) into LDS
    for (int idx = t; idx < T_ * 4; idx += 320) {
      const int s = idx & (T_ - 1), b = idx >> 9;
      float4 xv = *(const float4*)(x_in + (size_t)((bg0 + b) * T_ + s) * F_);
      sh_xq[s][b] = pack4bf(xv.x, xv.y, xv.z, xv.w);
    }
  }

  if (wv == 4) {
    // ================= HELPER WAVE =================
    // fw^T A-frags: A[m=f][k] = fw[k][f], rows 4-15 zero
    const float* fw = fcw_all + lyr * H_ * F_;
    const float* fb = fcb_all + lyr * F_;
    FragU Af[8];
    #pragma unroll
    for (int ks = 0; ks < 8; ++ks) {
      FragU f;
      #pragma unroll
      for (int j = 0; j < 8; ++j) {
        const int k = ks * 32 + quad * 8 + j;
        f.v[j] = (sub < 4) ? (short)f2bf(fw[k * 4 + sub]) : (short)0;
      }
      Af[ks] = f;
    }
    const float fb0 = fb[0], fb1 = fb[1], fb2 = fb[2], fb3 = fb[3];
    const int bl = sub & 3;

    if (role == 1) {
      // consumer prologue: poll slots [0,16): lane -> slot lane>>2, batch lane&3
      const int slot = lane >> 2, b = lane & 3;
      unsigned long long v;
      while ((v = __hip_atomic_load(&g_mbq[slot][bg0 + b], __ATOMIC_RELAXED,
                                    __HIP_MEMORY_SCOPE_AGENT)) == 0ull)
        __builtin_amdgcn_s_sleep(1);
      sh_xq[slot][b] = v;
    }
    __syncthreads();

    for (int i = 0; i <= T_; ++i) {
      if (role == 0) {
        if (i >= 1) {                      // projection of h[i-1]
          const char* hp = (const char*)sh_h + ((i + 1) & 1) * 2176;
          f32x4 pa = {fb0, fb1, fb2, fb3};
          #pragma unroll
          for (int ks = 0; ks < 8; ++ks) {
            FragU Bh;
            Bh.u = *(const uint4*)(hp + bl * 544 + ((ks * 32 + quad * 8) << 1));
            pa = __builtin_amdgcn_mfma_f32_16x16x32_bf16(Af[ks].v, Bh.v, pa, 0, 0, 0);
          }
          if (lane < 4) {
            float p0 = pa[0], p1 = pa[1], p2 = pa[2], p3 = pa[3];
            float inv = 1.f / fmaxf(sqrtf(p0*p0 + p1*p1 + p2*p2 + p3*p3), 1e-12f);
            sh_hold[(i - 1) & (KB_ - 1)][lane] = pack4bf(p0*inv, p1*inv, p2*inv, p3*inv);
          }
          if ((i & (KB_ - 1)) == 0 && lane < 32) {   // publish [i-8, i): 1 store/lane
            const int slot = i - KB_ + (lane >> 2), b = lane & 3;
            __hip_atomic_store(&g_mbq[slot][bg0 + b], sh_hold[slot & (KB_ - 1)][b],
                               __ATOMIC_RELAXED, __HIP_MEMORY_SCOPE_AGENT);
          }
        }
      } else {
        if ((i & (KB_ - 1)) == 0 && i >= KB_ && lane < 32) {  // poll [i+8, i+16)
          const int slot = i + KB_ + (lane >> 2), b = lane & 3;
          if (slot < T_) {
            unsigned long long v;
            while ((v = __hip_atomic_load(&g_mbq[slot][bg0 + b], __ATOMIC_RELAXED,
                                          __HIP_MEMORY_SCOPE_AGENT)) == 0ull)
              __builtin_amdgcn_s_sleep(1);
            sh_xq[slot][b] = v;
          }
        }
        if (i == T_) {                     // final projection -> output
          const char* hp = (const char*)sh_h + ((T_ - 1) & 1) * 2176;
          f32x4 pa = {fb0, fb1, fb2, fb3};
          #pragma unroll
          for (int ks = 0; ks < 8; ++ks) {
            FragU Bh;
            Bh.u = *(const uint4*)(hp + bl * 544 + ((ks * 32 + quad * 8) << 1));
            pa = __builtin_amdgcn_mfma_f32_16x16x32_bf16(Af[ks].v, Bh.v, pa, 0, 0, 0);
          }
          if (lane < 4) {
            float p0 = pa[0], p1 = pa[1], p2 = pa[2], p3 = pa[3];
            float inv = 1.f / fmaxf(sqrtf(p0*p0 + p1*p1 + p2*p2 + p3*p3), 1e-12f);
            *(float4*)(out_final + (bg0 + lane) * F_) =
                make_float4(p0 * inv, p1 * inv, p2 * inv, p3 * inv);
          }
        }
      }
      __syncthreads();
    }
  } else {
    // ================= COMPUTE WAVES =================
    const int u  = wv * 16 + sub;   // B n-col / D col
    const int ba = sub >> 2;        // A-side row -> batch
    const int qa = sub & 3;         // A-side row -> q

    FragU Bf[32], Bx[4];
    float bv[4][4];
    {
      const float* Cc[4] = {uhr, uhi, uhj, uhk};
      const float* Xc[4] = {wxr, wxi, wxj, wxk};
      const float* wb = wxb_all + lyr * 4 * H_;
      #pragma unroll
      for (int g = 0; g < 4; ++g) {
        #pragma unroll
        for (int ks = 0; ks < 8; ++ks) {
          const int d  = ks >> 1;
          const int pp = (ks & 1) * 32 + quad * 8;
          const float* src = Cc[d] + (size_t)((lyr * 4 + g) * 64 + pp) * 64 + u;
          FragU f;
          #pragma unroll
          for (int j = 0; j < 8; ++j) f.v[j] = (short)f2bf(src[j * 64]);
          Bf[g * 8 + ks] = f;
        }
        FragU fx; fx.w[0] = 0; fx.w[1] = 0; fx.w[2] = 0; fx.w[3] = 0;
        if (quad == 0) {
          unsigned e0 = f2bf(Xc[0][(lyr * 4 + g) * 64 + u]);
          unsigned e1 = f2bf(Xc[1][(lyr * 4 + g) * 64 + u]);
          unsigned e2 = f2bf(Xc[2][(lyr * 4 + g) * 64 + u]);
          unsigned e3 = f2bf(Xc[3][(lyr * 4 + g) * 64 + u]);
          fx.w[0] = e0 | (e1 << 16);
          fx.w[1] = e2 | (e3 << 16);
        }
        Bx[g] = fx;
        #pragma unroll
        for (int r = 0; r < 4; ++r) bv[g][r] = wb[g * 256 + r * 64 + u];
      }
    }
    unsigned smask[4], smx[4];
    int xsh[4], aoff[8];
    #pragma unroll
    for (int d = 0; d < 4; ++d) {
      const int a = qa ^ d;
      const bool neg = (QSIGN_MASK >> (a * 4 + qa)) & 1;
      smask[d] = neg ? 0x80008000u : 0u;
      smx[d]   = neg ? 0x8000u : 0u;
      xsh[d]   = 16 * a;
    }
    #pragma unroll
    for (int ks = 0; ks < 8; ++ks)
      aoff[ks] = ba * 544 + (((qa ^ (ks >> 1)) * 64 + (ks & 1) * 32 + quad * 8) << 1);

    float cs[4] = {0.f, 0.f, 0.f, 0.f};
    char* hbase = (char*)sh_h;
    __syncthreads();

    for (int i = 0; i <= T_; ++i) {
      if (i < T_) {
        const char* hp = hbase + ((i + 1) & 1) * 2176;   // h[i-1]
        unsigned long long xq = sh_xq[i][ba];
        FragU Ax; Ax.w[0] = 0; Ax.w[1] = 0; Ax.w[2] = 0; Ax.w[3] = 0;
        if (quad == 0) {
          unsigned e0 = ((unsigned)(xq >> xsh[0]) & 0xffffu) ^ smx[0];
          unsigned e1 = ((unsigned)(xq >> xsh[1]) & 0xffffu) ^ smx[1];
          unsigned e2 = ((unsigned)(xq >> xsh[2]) & 0xffffu) ^ smx[2];
          unsigned e3 = ((unsigned)(xq >> xsh[3]) & 0xffffu) ^ smx[3];
          Ax.w[0] = e0 | (e1 << 16);
          Ax.w[1] = e2 | (e3 << 16);
        }
        f32x4 acc0 = {bv[0][0], bv[0][1], bv[0][2], bv[0][3]};
        f32x4 acc1 = {bv[1][0], bv[1][1], bv[1][2], bv[1][3]};
        f32x4 acc2 = {bv[2][0], bv[2][1], bv[2][2], bv[2][3]};
        f32x4 acc3 = {bv[3][0], bv[3][1], bv[3][2], bv[3][3]};
        acc0 = __builtin_amdgcn_mfma_f32_16x16x32_bf16(Ax.v, Bx[0].v, acc0, 0, 0, 0);
        acc1 = __builtin_amdgcn_mfma_f32_16x16x32_bf16(Ax.v, Bx[1].v, acc1, 0, 0, 0);
        acc2 = __builtin_amdgcn_mfma_f32_16x16x32_bf16(Ax.v, Bx[2].v, acc2, 0, 0, 0);
        acc3 = __builtin_amdgcn_mfma_f32_16x16x32_bf16(Ax.v, Bx[3].v, acc3, 0, 0, 0);
        #pragma unroll
        for (int ks = 0; ks < 8; ++ks) {
          FragU A;
          A.u = *(const uint4*)(hp + aoff[ks]);
          const unsigned m = smask[ks >> 1];
          A.w[0] ^= m; A.w[1] ^= m; A.w[2] ^= m; A.w[3] ^= m;
          acc0 = __builtin_amdgcn_mfma_f32_16x16x32_bf16(A.v, Bf[0 * 8 + ks].v, acc0, 0, 0, 0);
          acc1 = __builtin_amdgcn_mfma_f32_16x16x32_bf16(A.v, Bf[1 * 8 + ks].v, acc1, 0, 0, 0);
          acc2 = __builtin_amdgcn_mfma_f32_16x16x32_bf16(A.v, Bf[2 * 8 + ks].v, acc2, 0, 0, 0);
          acc3 = __builtin_amdgcn_mfma_f32_16x16x32_bf16(A.v, Bf[3 * 8 + ks].v, acc3, 0, 0, 0);
        }
        // fully in-lane gates: b=quad, col = r*64+u
        char* hw = hbase + (i & 1) * 2176 + quad * 544;
        #pragma unroll
        for (int r = 0; r < 4; ++r) {
          float fg = fast_sigmoid(acc0[r]);
          float ig = fast_sigmoid(acc1[r]);
          float og = fast_sigmoid(acc2[r]);
          float cv = fast_tanh(acc3[r]);
          cs[r] = ig * cv + fg * cs[r];
          float h = og * fast_tanh(cs[r]);
          *(unsigned short*)(hw + ((r * 64 + u) << 1)) = (unsigned short)f2bf(h);
        }
      }
      __syncthreads();
    }
  }
}

extern "C" void kernel_launch(void* const* d_in, const int* in_sizes, int n_in,
                              void* d_out, int out_size, void* d_ws, size_t ws_size,
                              hipStream_t stream) {
  const float* x   = (const float*)d_in[0];
  const float* wxr = (const float*)d_in[1];
  const float* wxi = (const float*)d_in[2];
  const float* wxj = (const float*)d_in[3];
  const float* wxk = (const float*)d_in[4];
  const float* wxb = (const float*)d_in[5];
  const float* uhr = (const float*)d_in[6];
  const float* uhi = (const float*)d_in[7];
  const float* uhj = (const float*)d_in[8];
  const float* uhk = (const float*)d_in[9];
  const float* fcw = (const float*)d_in[10];
  const float* fcb = (const float*)d_in[11];
  float* out = (float*)d_out;

  zero_mb<<<dim3(T_ * B_ / 256), dim3(256), 0, stream>>>();
  qlstm_pipe<<<dim3(64), dim3(320), 0, stream>>>(
      x, uhr, uhi, uhj, uhk, wxr, wxi, wxj, wxk, wxb, fcw, fcb, out);
}